// Round 1
// 365.871 us; speedup vs baseline: 1.0343x; 1.0343x over previous
//
#include <hip/hip_runtime.h>

// DenseGINEConv fused kernel for MI355X (gfx950).
// B=4, N=512, F=64, H=128, fp32. Memory-bound on edge_attr (256 MiB read-once).
// Round 3: TJ=8 so each wave's per-i ea footprint is 2 KiB contiguous
// (32 B/lane: two float4 at adjacent f-halves, 8 consecutive j rows/wave).
// ea loads are non-temporal (read-once stream, keep x/adj/W in cache).
// Grid = 256 blocks x 512 thr = 1 block/CU, 8 waves/CU.

namespace {

constexpr int Bc = 4;
constexpr int Nc = 512;
constexpr int Fc = 64;
constexpr int Hc = 128;
constexpr int TJ = 8;          // j-tile per block
constexpr int TH = 512;        // threads per block
constexpr float NEG = 0.01f;

typedef float f4 __attribute__((ext_vector_type(4)));

__device__ __forceinline__ float lrelu(float z) {
  return fmaxf(z, z * NEG);
}

__device__ __forceinline__ f4 lrelu4(f4 z) {
  f4 zn = z * NEG;
  f4 r;
  r.x = fmaxf(z.x, zn.x);
  r.y = fmaxf(z.y, zn.y);
  r.z = fmaxf(z.z, zn.z);
  r.w = fmaxf(z.w, zn.w);
  return r;
}

__global__ __launch_bounds__(TH, 2) void gine_fused(
    const float* __restrict__ x,    // (B,N,F)
    const float* __restrict__ adj,  // (B,N,N)
    const float* __restrict__ ea,   // (B,N,N,F)
    const int* __restrict__ mask,   // (B,N) int32 0/1
    const float* __restrict__ W1,   // (F,H)
    const float* __restrict__ b1,   // (H)
    const float* __restrict__ W2,   // (H,F)
    const float* __restrict__ b2,   // (F)
    float* __restrict__ out)        // (B,N,F)
{
  const int blk = blockIdx.x;            // 0 .. B*N/TJ-1 = 255
  const int b   = blk >> 6;              // blk / (N/TJ = 64)
  const int j0  = (blk & 63) * TJ;
  const int tid = threadIdx.x;
  const int f8  = tid & 7;               // 8-float group over F: f = f8*8 .. f8*8+7
  const int jl  = (tid >> 3) & 7;        // which j within tile
  const int ip  = tid >> 6;              // 0..7 partial over source i (= wave id)

  __shared__ float s_adj[Nc][TJ];        // 16 KiB: [i][jl] = adj[b,i,j0+jl]
  __shared__ f4    s_pA[TH];             // 8 KiB
  __shared__ f4    s_pB[TH];             // 8 KiB
  __shared__ float s_out[TJ][Fc];        // 2 KiB
  __shared__ float s_hid[TJ][Hc];        // 4 KiB

  // ---- stage adj columns j0..j0+7 (16 KiB, once per block) ----
  const float* adjb = adj + (size_t)b * Nc * Nc;
  {
    f4* s_adj4 = reinterpret_cast<f4*>(&s_adj[0][0]);
    #pragma unroll
    for (int k = 0; k < 2; ++k) {
      const int fl   = tid + k * TH;     // flat f4 index 0..1023
      const int i    = fl >> 1;
      const int half = fl & 1;
      s_adj4[fl] = *reinterpret_cast<const f4*>(adjb + (size_t)i * Nc + j0 + half * 4);
    }
  }
  __syncthreads();

  // ---- aggregation: acc[jl][f] = sum_i lrelu(adj[b,i,j0+jl]*(x[b,i,f]+ea[b,i,j0+jl,f])) ----
  const f4* xb4 = reinterpret_cast<const f4*>(x + (size_t)b * Nc * Fc);
  const f4* ep  = reinterpret_cast<const f4*>(ea)
                + ((size_t)b * Nc * Nc + (size_t)(j0 + jl)) * (Fc / 4) + f8 * 2;
  constexpr size_t ISTR = (size_t)Nc * (Fc / 4);   // 8192 f4 per i

  f4 accA = {0.f, 0.f, 0.f, 0.f};
  f4 accB = {0.f, 0.f, 0.f, 0.f};
  #pragma unroll 4
  for (int i = ip; i < Nc; i += 8) {
    const float a = s_adj[i][jl];                  // broadcast within 8-lane group
    const f4* p  = ep + (size_t)i * ISTR;
    const f4 e0  = __builtin_nontemporal_load(p);      // wave: 2 KiB contiguous
    const f4 e1  = __builtin_nontemporal_load(p + 1);
    const f4 x0  = xb4[i * (Fc / 4) + f8 * 2];         // L1/L2 hit
    const f4 x1  = xb4[i * (Fc / 4) + f8 * 2 + 1];
    accA += lrelu4(a * (x0 + e0));
    accB += lrelu4(a * (x1 + e1));
  }

  // ---- reduce 8 ip-partials; partials for (jl,f8) live at stride 64 ----
  s_pA[tid] = accA;
  s_pB[tid] = accB;
  __syncthreads();
  #pragma unroll
  for (int s = 256; s >= 64; s >>= 1) {
    if (tid < s) {
      s_pA[tid] += s_pA[tid + s];
      s_pB[tid] += s_pB[tid + s];
    }
    __syncthreads();
  }

  // ---- add self-loop x[b,j,:] (EPS=0), stash 8 rows ----
  if (tid < 64) {
    const int row = jl;                  // tid>>3 for tid<64
    f4 r0 = s_pA[tid];
    f4 r1 = s_pB[tid];
    r0 += xb4[(j0 + row) * (Fc / 4) + f8 * 2];
    r1 += xb4[(j0 + row) * (Fc / 4) + f8 * 2 + 1];
    f4* so = reinterpret_cast<f4*>(&s_out[row][0]);
    so[f8 * 2]     = r0;
    so[f8 * 2 + 1] = r1;
  }
  __syncthreads();

  // ---- MLP stage 1: hid[row][h] = lrelu(row @ W1 + b1); 2 rows/thread ----
  {
    const int h  = tid & 127;
    const int r0 = (tid >> 7) * 2;       // 0,2,4,6
    float hv0 = b1[h];
    float hv1 = hv0;
    #pragma unroll 8
    for (int f = 0; f < Fc; ++f) {
      const float w = W1[f * Hc + h];    // coalesced over h, L1-resident
      hv0 = fmaf(s_out[r0][f],     w, hv0);
      hv1 = fmaf(s_out[r0 + 1][f], w, hv1);
    }
    s_hid[r0][h]     = lrelu(hv0);
    s_hid[r0 + 1][h] = lrelu(hv1);
  }
  __syncthreads();

  // ---- MLP stage 2: o = hid @ W2 + b2, masked write; 1 row/thread ----
  {
    const int f   = tid & 63;
    const int row = tid >> 6;            // 0..7
    float o = b2[f];
    #pragma unroll 8
    for (int h = 0; h < Hc; ++h)
      o = fmaf(s_hid[row][h], W2[h * Fc + f], o);
    const int rowg = b * Nc + j0 + row;
    out[(size_t)rowg * Fc + f] = (mask[rowg] != 0) ? o : 0.f;
  }
}

} // namespace

extern "C" void kernel_launch(void* const* d_in, const int* in_sizes, int n_in,
                              void* d_out, int out_size, void* d_ws, size_t ws_size,
                              hipStream_t stream) {
  const float* x    = (const float*)d_in[0];
  const float* adj  = (const float*)d_in[1];
  const float* ea   = (const float*)d_in[2];
  const int*   mask = (const int*)d_in[3];
  const float* W1   = (const float*)d_in[4];
  const float* b1   = (const float*)d_in[5];
  const float* W2   = (const float*)d_in[6];
  const float* b2   = (const float*)d_in[7];
  float* out = (float*)d_out;

  gine_fused<<<dim3(Bc * Nc / TJ), dim3(TH), 0, stream>>>(
      x, adj, ea, mask, W1, b1, W2, b2, out);
}